// Round 3
// baseline (592.110 us; speedup 1.0000x reference)
//
#include <hip/hip_runtime.h>
#include <math.h>

#define NB 2048
#define NS 512
#define ND 96
#define ST_H 100   // sh stride (shorts): 2*ST_H mod 32 banks spreads quads by 8 -> conflict-free u16 C-writes
#define ST_S 104   // stg stride (shorts): multiple of 8 (16B-aligned b128 frag reads), 2-way max conflict

typedef __attribute__((ext_vector_type(8))) short short8;
typedef __attribute__((ext_vector_type(4))) float floatx4;
typedef __attribute__((ext_vector_type(2))) unsigned uint2v;

__device__ __forceinline__ unsigned f2bfu(float f) {
    union { float f; unsigned u; } c; c.f = f;
    unsigned u = c.u;
    u += 0x7FFF + ((u >> 16) & 1);   // RNE
    return u >> 16;
}
__device__ __forceinline__ unsigned pack2(float a, float b) {
    return f2bfu(a) | (f2bfu(b) << 16);
}
__device__ __forceinline__ float bf2f(short s) {
    union { unsigned u; float f; } c;
    c.u = ((unsigned)(unsigned short)s) << 16;
    return c.f;
}
__device__ __forceinline__ float sigm(float x) {
    return 1.0f / (1.0f + __expf(-x));
}

__global__ __launch_bounds__(1024, 4)
void attn_fused(const float* __restrict__ seq,   // (B,S,96)
                const float* __restrict__ tgt,   // (B,1,96)
                const int*   __restrict__ mask,  // (B,513,1) int32
                const float* __restrict__ w1,    // (96,96) [e][d]
                const float* __restrict__ b1,    // (96)
                const float* __restrict__ w2,    // (96,96) [e][d]
                const float* __restrict__ b2,    // (96)
                float* __restrict__ out)         // (B,96)
{
    __shared__ short sh[NS * ST_H];      // seq_h bf16, 102,400 B
    __shared__ short stg[128 * ST_S];    // seq chunk bf16, 26,624 B
    __shared__ short w1f[18 * 64 * 8];   // W1 B-fragments, 18,432 B
    __shared__ float sc2[2][NS];         // score partials per e-half
    __shared__ float atn[NS];            // attn weights
    __shared__ float th[ND];             // tgt_h
    __shared__ float red1[16], red2[16];
    __shared__ float osum[8][ND];

    const int b    = blockIdx.x;
    const int tid  = threadIdx.x;        // 0..1023
    const int lane = tid & 63;
    const int wave = tid >> 6;           // 0..15
    const int l15  = lane & 15;
    const int quad = lane >> 4;
    const int tile  = wave & 7;          // s-tile within chunk (16 rows)
    const int ehalf = wave >> 3;         // 0: t=0..2, 1: t=3..5
    const int tbase = ehalf * 3;

    // ---- stage W1 -> bf16 B-fragments in LDS (frag(t,kk), lane-major, b128) ----
    for (int idx = tid; idx < 1152; idx += 1024) {   // 96 rows x 12 chunks of 8
        const int e  = idx / 12;
        const int dc = idx - 12 * e;
        const int kk = dc >> 2;
        const int q  = dc & 3;
        const float* p = w1 + e * ND + kk * 32 + q * 8;
        floatx4 p0 = *(const floatx4*)(p);
        floatx4 p1 = *(const floatx4*)(p + 4);
        short8 v;
        v[0]=(short)f2bfu(p0[0]); v[1]=(short)f2bfu(p0[1]);
        v[2]=(short)f2bfu(p0[2]); v[3]=(short)f2bfu(p0[3]);
        v[4]=(short)f2bfu(p1[0]); v[5]=(short)f2bfu(p1[1]);
        v[6]=(short)f2bfu(p1[2]); v[7]=(short)f2bfu(p1[3]);
        const int t = e >> 4, r = e & 15;
        *(short8*)&w1f[(((t * 3 + kk) * 64) + q * 16 + r) * 8] = v;
    }

    // ---- tgt_h[e] = dot(tgt[b], w2[e,:]) + b2[e] (fp32) ----
    if (tid < ND) {
        const float* tv = tgt + (size_t)b * ND;
        const float* wr = w2 + tid * ND;
        float acc = b2[tid];
        #pragma unroll
        for (int d = 0; d < ND; d += 4) {
            acc += tv[d]*wr[d] + tv[d+1]*wr[d+1] + tv[d+2]*wr[d+2] + tv[d+3]*wr[d+3];
        }
        th[tid] = acc;
    }
    __syncthreads();

    float tgtv[3], biasv[3];
    #pragma unroll
    for (int j = 0; j < 3; ++j) {
        tgtv[j]  = th[16 * (tbase + j) + l15];
        biasv[j] = b1[16 * (tbase + j) + l15];
    }

    // ---- main loop over 4 chunks of 128 s-rows ----
    for (int c = 0; c < 4; ++c) {
        // stage chunk: coalesced float4 loads, cvt bf16, padded LDS tile
        const float* gbase = seq + ((size_t)b * NS + c * 128) * ND;
        #pragma unroll
        for (int i = 0; i < 3; ++i) {
            const int fi = (tid + i * 1024) * 4;     // 0..12284, 96%4==0 so no row straddle
            floatx4 v = *(const floatx4*)(gbase + fi);
            const int r   = fi / 96;
            const int col = fi - 96 * r;
            uint2v pkd;
            pkd[0] = pack2(v[0], v[1]);
            pkd[1] = pack2(v[2], v[3]);
            *(uint2v*)&stg[r * ST_S + col] = pkd;
        }
        __syncthreads();

        // A-fragments from LDS (one b128 per kk)
        short8 af[3];
        #pragma unroll
        for (int kk = 0; kk < 3; ++kk) {
            af[kk] = *(const short8*)&stg[(tile * 16 + l15) * ST_S + kk * 32 + quad * 8];
        }

        float ps0 = 0.f, ps1 = 0.f, ps2 = 0.f, ps3 = 0.f;
        const int s0 = c * 128 + tile * 16;
        #pragma unroll
        for (int j = 0; j < 3; ++j) {
            const int t = tbase + j;
            floatx4 acc = { biasv[j], biasv[j], biasv[j], biasv[j] };
            #pragma unroll
            for (int kk = 0; kk < 3; ++kk) {
                const short8 bf = *(const short8*)&w1f[((t * 3 + kk) * 64 + lane) * 8];
                acc = __builtin_amdgcn_mfma_f32_16x16x32_bf16(af[kk], bf, acc, 0, 0, 0);
            }
            const int e = 16 * t + l15;
            short* dst = &sh[(s0 + quad * 4) * ST_H + e];
            dst[0]          = (short)f2bfu(acc[0]);
            dst[ST_H]       = (short)f2bfu(acc[1]);
            dst[2 * ST_H]   = (short)f2bfu(acc[2]);
            dst[3 * ST_H]   = (short)f2bfu(acc[3]);
            const float thv = tgtv[j];
            ps0 += sigm(acc[0] + thv);
            ps1 += sigm(acc[1] + thv);
            ps2 += sigm(acc[2] + thv);
            ps3 += sigm(acc[3] + thv);
        }
        // reduce partial scores over the 16 e-lanes of each quad
        #pragma unroll
        for (int off = 1; off < 16; off <<= 1) {
            ps0 += __shfl_xor(ps0, off, 64);
            ps1 += __shfl_xor(ps1, off, 64);
            ps2 += __shfl_xor(ps2, off, 64);
            ps3 += __shfl_xor(ps3, off, 64);
        }
        if (l15 == 0) {
            sc2[ehalf][s0 + quad * 4 + 0] = ps0;
            sc2[ehalf][s0 + quad * 4 + 1] = ps1;
            sc2[ehalf][s0 + quad * 4 + 2] = ps2;
            sc2[ehalf][s0 + quad * 4 + 3] = ps3;
        }
        __syncthreads();   // stg reuse + sc2/sh visibility
    }

    // ---- masked softmax over s ----
    float v = -1e30f;
    if (tid < NS) {
        v = sc2[0][tid] + sc2[1][tid];
        if (mask[(size_t)b * (NS + 1) + tid] != 0) v = -1e9f;
    }
    float mx = v;
    #pragma unroll
    for (int off = 1; off < 64; off <<= 1) mx = fmaxf(mx, __shfl_xor(mx, off, 64));
    if (lane == 0) red1[wave] = mx;
    __syncthreads();
    mx = red1[0];
    #pragma unroll
    for (int w = 1; w < 16; ++w) mx = fmaxf(mx, red1[w]);
    const float e0 = (tid < NS) ? __expf(v - mx) : 0.f;
    float ssum = e0;
    #pragma unroll
    for (int off = 1; off < 64; off <<= 1) ssum += __shfl_xor(ssum, off, 64);
    if (lane == 0) red2[wave] = ssum;
    __syncthreads();
    float tot = red2[0];
    #pragma unroll
    for (int w = 1; w < 16; ++w) tot += red2[w];
    if (tid < NS) atn[tid] = e0 * (1.0f / tot);
    __syncthreads();

    // ---- output: out[b,e] = sum_s attn[s] * seq_h[s,e] ----
    if (tid < 8 * ND) {
        const int g = tid / ND;          // 0..7: s-group of 64
        const int e = tid - g * ND;
        float acc = 0.f;
        const int sb = g * 64;
        #pragma unroll 4
        for (int s = sb; s < sb + 64; ++s) {
            acc += atn[s] * bf2f(sh[s * ST_H + e]);
        }
        osum[g][e] = acc;
    }
    __syncthreads();
    if (tid < ND) {
        float a = 0.f;
        #pragma unroll
        for (int g = 0; g < 8; ++g) a += osum[g][tid];
        out[(size_t)b * ND + tid] = a;
    }
}

extern "C" void kernel_launch(void* const* d_in, const int* in_sizes, int n_in,
                              void* d_out, int out_size, void* d_ws, size_t ws_size,
                              hipStream_t stream) {
    const float* seq  = (const float*)d_in[0];
    const float* tgt  = (const float*)d_in[1];
    const int*   mask = (const int*)d_in[2];
    const float* w1   = (const float*)d_in[3];
    const float* b1   = (const float*)d_in[4];
    const float* w2   = (const float*)d_in[5];
    const float* b2   = (const float*)d_in[6];
    float* out = (float*)d_out;
    attn_fused<<<dim3(NB), dim3(1024), 0, stream>>>(seq, tgt, mask, w1, b1, w2, b2, out);
}